// Round 1
// baseline (481.007 us; speedup 1.0000x reference)
//
#include <hip/hip_runtime.h>
#include <hip/hip_cooperative_groups.h>

namespace cg = cooperative_groups;

// Problem constants
#define EDIM 1024

constexpr int AUD_ELEMS  = 32 * 1024;          // 32768  (audio_output 32x1024)
constexpr int CONN_ELEMS = 1024 * 4096;        // 4194304 (connections copy)
constexpr int INW_ELEMS  = 3 * 1024 * 1024;    // 3145728 (in_proj_w copy)
constexpr int OUTW_ELEMS = 1024 * 1024;        // 1048576 (out_proj_w copy)

constexpr int AUD_F4   = AUD_ELEMS / 4;        // 8192
constexpr int CONN_F4  = CONN_ELEMS / 4;       // 1048576
constexpr int INW_F4   = INW_ELEMS / 4;        // 786432
constexpr int OUTW_F4  = OUTW_ELEMS / 4;       // 262144
constexpr int TOTAL_F4 = AUD_F4 + CONN_F4 + INW_F4 + OUTW_F4;  // 2105344

constexpr int GRID_BLOCKS = 1024;
constexpr int NTHREADS    = GRID_BLOCKS * 256; // 262144

// ---------------------------------------------------------------------------
// C[32 x 1024] = A[32 x 1024] @ B[1024 x 1024]^T + bias   (row-dot form)
// One wave per (e, n-group-of-8): 4096 waves == exactly our 1024x256 grid.
// ---------------------------------------------------------------------------
__device__ __forceinline__ void gemm_rowdot(
    const float* __restrict__ A, const float* __restrict__ B,
    const float* __restrict__ bias, float* __restrict__ C,
    int bid, int tid)
{
    int gw   = (bid << 2) | (tid >> 6);   // global wave id [0,4096)
    int lane = tid & 63;
    int e    = gw & 1023;
    int n0   = (gw >> 10) << 3;

    const float4* Br = (const float4*)(B + (size_t)e * EDIM);
    float4 b0 = Br[lane], b1 = Br[lane + 64], b2 = Br[lane + 128], b3 = Br[lane + 192];
    float be = bias[e];

#pragma unroll
    for (int i = 0; i < 8; ++i) {
        int n = n0 + i;
        const float4* Ar = (const float4*)(A + (size_t)n * EDIM);
        float4 a0 = Ar[lane], a1 = Ar[lane + 64], a2 = Ar[lane + 128], a3 = Ar[lane + 192];
        float s = a0.x*b0.x + a0.y*b0.y + a0.z*b0.z + a0.w*b0.w;
        s += a1.x*b1.x + a1.y*b1.y + a1.z*b1.z + a1.w*b1.w;
        s += a2.x*b2.x + a2.y*b2.y + a2.z*b2.z + a2.w*b2.w;
        s += a3.x*b3.x + a3.y*b3.y + a3.z*b3.z + a3.w*b3.w;
#pragma unroll
        for (int off = 32; off > 0; off >>= 1) s += __shfl_down(s, off);
        if (lane == 0) C[(size_t)n * EDIM + e] = s + be;
    }
}

// ---------------------------------------------------------------------------
// audio[32 x 1024] += attn[32 x 1024] @ connections[:, :1024]
// 128 blocks = (16 k-chunks of 64) x (8 n-groups of 4); atomic split-k into
// the pre-zeroed audio region (zeroed during the phase-A copy pass).
// ---------------------------------------------------------------------------
__device__ __forceinline__ void audio_tile(
    const float* __restrict__ attn, const float* __restrict__ conn,
    float* __restrict__ out, float* sa, int bid, int tid)
{
    int g  = bid & 7;       // n-group
    int kc = bid >> 3;      // k-chunk
    int n0 = g * 4;
    int k0 = kc * 64;
    int t  = tid;           // j-quad index: j = 4t .. 4t+3

    sa[t] = attn[(size_t)(n0 + (t >> 6)) * EDIM + k0 + (t & 63)];
    __syncthreads();

    const float4* c4 = (const float4*)conn;   // 1024 float4 per row (4096 cols)
    float4 acc0 = {0,0,0,0}, acc1 = {0,0,0,0}, acc2 = {0,0,0,0}, acc3 = {0,0,0,0};
#pragma unroll 4
    for (int k = 0; k < 64; ++k) {
        float4 c = c4[(size_t)(k0 + k) * 1024 + t];
        float a0v = sa[k], a1v = sa[64 + k], a2v = sa[128 + k], a3v = sa[192 + k];
        acc0.x += a0v*c.x; acc0.y += a0v*c.y; acc0.z += a0v*c.z; acc0.w += a0v*c.w;
        acc1.x += a1v*c.x; acc1.y += a1v*c.y; acc1.z += a1v*c.z; acc1.w += a1v*c.w;
        acc2.x += a2v*c.x; acc2.y += a2v*c.y; acc2.z += a2v*c.z; acc2.w += a2v*c.w;
        acc3.x += a3v*c.x; acc3.y += a3v*c.y; acc3.z += a3v*c.z; acc3.w += a3v*c.w;
    }

    float* o0 = out + (size_t)(n0 + 0) * 1024 + 4 * t;
    float* o1 = out + (size_t)(n0 + 1) * 1024 + 4 * t;
    float* o2 = out + (size_t)(n0 + 2) * 1024 + 4 * t;
    float* o3 = out + (size_t)(n0 + 3) * 1024 + 4 * t;
    atomicAdd(o0 + 0, acc0.x); atomicAdd(o0 + 1, acc0.y); atomicAdd(o0 + 2, acc0.z); atomicAdd(o0 + 3, acc0.w);
    atomicAdd(o1 + 0, acc1.x); atomicAdd(o1 + 1, acc1.y); atomicAdd(o1 + 2, acc1.z); atomicAdd(o1 + 3, acc1.w);
    atomicAdd(o2 + 0, acc2.x); atomicAdd(o2 + 1, acc2.y); atomicAdd(o2 + 2, acc2.z); atomicAdd(o2 + 3, acc2.w);
    atomicAdd(o3 + 0, acc3.x); atomicAdd(o3 + 1, acc3.y); atomicAdd(o3 + 2, acc3.z); atomicAdd(o3 + 3, acc3.w);
}

// ---------------------------------------------------------------------------
// Single cooperative kernel:
//   Phase A: GEMM1 (vp = av_value @ Wv^T + bv) + full output copy/zero
//            (copy overlaps the latency-bound GEMM; zeroing audio is free)
//   Phase B: GEMM2 (attn = vp @ Wo^T + bo)
//   Phase C: audio = attn @ connections[:, :1024]  (blocks 0..127)
// STDP deltas are exactly zero (TAU_POS == TAU_NEG), so weights copy verbatim.
// ---------------------------------------------------------------------------
__global__ __launch_bounds__(256, 4) void fused_kernel(
    const float* __restrict__ av_value, const float* __restrict__ in_proj_w,
    const float* __restrict__ in_proj_b, const float* __restrict__ out_proj_w,
    const float* __restrict__ out_proj_b, const float* __restrict__ conn,
    float* __restrict__ out, float* __restrict__ vp, float* __restrict__ attn)
{
    cg::grid_group grid = cg::this_grid();
    __shared__ float sa[256];
    int bid = blockIdx.x, tid = threadIdx.x;

    // ---- Phase A ----
    gemm_rowdot(av_value, in_proj_w + 2 * EDIM * EDIM, in_proj_b + 2 * EDIM, vp,
                bid, tid);

    {
        const float4* cs = (const float4*)conn;
        const float4* is = (const float4*)in_proj_w;
        const float4* os = (const float4*)out_proj_w;
        float4* o4 = (float4*)out;
        for (int i = bid * 256 + tid; i < TOTAL_F4; i += NTHREADS) {
            float4 v;
            if (i < AUD_F4) {
                v = make_float4(0.f, 0.f, 0.f, 0.f);
            } else if (i < AUD_F4 + CONN_F4) {
                v = cs[i - AUD_F4];
            } else if (i < AUD_F4 + CONN_F4 + INW_F4) {
                v = is[i - (AUD_F4 + CONN_F4)];
            } else {
                v = os[i - (AUD_F4 + CONN_F4 + INW_F4)];
            }
            o4[i] = v;
        }
    }

    __threadfence();
    grid.sync();

    // ---- Phase B ----
    gemm_rowdot(vp, out_proj_w, out_proj_b, attn, bid, tid);

    __threadfence();
    grid.sync();

    // ---- Phase C ----
    if (bid < 128) audio_tile(attn, conn, out, sa, bid, tid);
}

extern "C" void kernel_launch(void* const* d_in, const int* in_sizes, int n_in,
                              void* d_out, int out_size, void* d_ws, size_t ws_size,
                              hipStream_t stream) {
    // setup_inputs order:
    // 0 av_value, 1 av_key, 2 av_query, 3 in_proj_w, 4 in_proj_b,
    // 5 out_proj_w, 6 out_proj_b, 7 connections
    const float* av_value   = (const float*)d_in[0];
    const float* in_proj_w  = (const float*)d_in[3];
    const float* in_proj_b  = (const float*)d_in[4];
    const float* out_proj_w = (const float*)d_in[5];
    const float* out_proj_b = (const float*)d_in[6];
    const float* conn       = (const float*)d_in[7];
    float* out = (float*)d_out;

    float* vp   = (float*)d_ws;            // 32x1024
    float* attn = vp + AUD_ELEMS;          // 32x1024

    void* args[] = { (void*)&av_value, (void*)&in_proj_w, (void*)&in_proj_b,
                     (void*)&out_proj_w, (void*)&out_proj_b, (void*)&conn,
                     (void*)&out, (void*)&vp, (void*)&attn };
    hipLaunchCooperativeKernel((void*)fused_kernel, dim3(GRID_BLOCKS), dim3(256),
                               args, 0, stream);
}

// Round 2
// 127.480 us; speedup vs baseline: 3.7732x; 3.7732x over previous
//
#include <hip/hip_runtime.h>

// Problem constants
#define EDIM 1024

constexpr int AUD_ELEMS  = 32 * 1024;          // 32768  (audio_output 32x1024)
constexpr int CONN_ELEMS = 1024 * 4096;        // 4194304 (connections copy)
constexpr int INW_ELEMS  = 3 * 1024 * 1024;    // 3145728 (in_proj_w copy)
constexpr int OUTW_ELEMS = 1024 * 1024;        // 1048576 (out_proj_w copy)

constexpr int AUD_F4   = AUD_ELEMS / 4;        // 8192
constexpr int CONN_F4  = CONN_ELEMS / 4;       // 1048576
constexpr int INW_F4   = INW_ELEMS / 4;        // 786432
constexpr int OUTW_F4  = OUTW_ELEMS / 4;       // 262144
constexpr int TOTAL_F4 = AUD_F4 + CONN_F4 + INW_F4 + OUTW_F4;  // 2105344

constexpr int A_BLOCKS   = 1024;
constexpr int A_NTHREADS = A_BLOCKS * 256;     // 262144

// Fused tail: KC = k-chunk per block. 256 blocks = (1024/KC kc) x (8 n-groups).
constexpr int KC       = 32;
constexpr int NB_TAIL  = (1024 / KC) * 8;      // 256

// ---------------------------------------------------------------------------
// Dispatch A:  vp[32x1024] = av_value @ Wv^T + bv   (one wave per (e, n-grp-8))
// then grid-stride copy: zero audio region, copy conn/in_proj_w/out_proj_w
// verbatim into the output (STDP delta == 0 exactly since TAU_POS == TAU_NEG).
// No grid sync needed: the dispatch boundary is the barrier.
// ---------------------------------------------------------------------------
__global__ __launch_bounds__(256) void gemm1_copy_kernel(
    const float* __restrict__ A, const float* __restrict__ B,
    const float* __restrict__ bias, float* __restrict__ C,
    const float4* __restrict__ conn4, const float4* __restrict__ inw4,
    const float4* __restrict__ outw4, float4* __restrict__ out4)
{
    int bid = blockIdx.x, tid = threadIdx.x;
    int gw   = (bid << 2) | (tid >> 6);   // global wave id [0,4096)
    int lane = tid & 63;
    int e    = gw & 1023;
    int n0   = (gw >> 10) << 3;

    const float4* Br = (const float4*)(B + (size_t)e * EDIM);
    float4 b0 = Br[lane], b1 = Br[lane + 64], b2 = Br[lane + 128], b3 = Br[lane + 192];
    float be = bias[e];

#pragma unroll
    for (int i = 0; i < 8; ++i) {
        int n = n0 + i;
        const float4* Ar = (const float4*)(A + (size_t)n * EDIM);
        float4 a0 = Ar[lane], a1 = Ar[lane + 64], a2 = Ar[lane + 128], a3 = Ar[lane + 192];
        float s = a0.x*b0.x + a0.y*b0.y + a0.z*b0.z + a0.w*b0.w;
        s += a1.x*b1.x + a1.y*b1.y + a1.z*b1.z + a1.w*b1.w;
        s += a2.x*b2.x + a2.y*b2.y + a2.z*b2.z + a2.w*b2.w;
        s += a3.x*b3.x + a3.y*b3.y + a3.z*b3.z + a3.w*b3.w;
#pragma unroll
        for (int off = 32; off > 0; off >>= 1) s += __shfl_down(s, off);
        if (lane == 0) C[(size_t)n * EDIM + e] = s + be;
    }

    // ---- output copy / audio-zero (independent work, overlaps GEMM latency) ----
    for (int i = bid * 256 + tid; i < TOTAL_F4; i += A_NTHREADS) {
        float4 v;
        if (i < AUD_F4) {
            v = make_float4(0.f, 0.f, 0.f, 0.f);
        } else if (i < AUD_F4 + CONN_F4) {
            v = conn4[i - AUD_F4];
        } else if (i < AUD_F4 + CONN_F4 + INW_F4) {
            v = inw4[i - (AUD_F4 + CONN_F4)];
        } else {
            v = outw4[i - (AUD_F4 + CONN_F4 + INW_F4)];
        }
        out4[i] = v;
    }
}

// ---------------------------------------------------------------------------
// Dispatch B: fused gemm2 + audio.  Block (kc, g) computes its own attn tile
//   attn[n0..n0+3][k0..k0+KC) = vp[n0..n0+3,:] @ Wo[k0..k0+KC,:]^T + bo
// (each attn element computed exactly once across the grid -> zero redundancy,
// attn never hits HBM), then accumulates
//   out[n0..n0+3][j] += sum_k attn_tile[.][k] * conn[k0+k][j],  j in [0,1024)
// via atomicAdd into the audio region zeroed by dispatch A.
// ---------------------------------------------------------------------------
__global__ __launch_bounds__(256) void tail_kernel(
    const float* __restrict__ vp, const float* __restrict__ Wo,
    const float* __restrict__ bo, const float* __restrict__ conn,
    float* __restrict__ out)
{
    int g  = blockIdx.x & 7;       // n-group
    int kc = blockIdx.x >> 3;      // k-chunk
    int n0 = g * 4;
    int k0 = kc * KC;
    int tid  = threadIdx.x;
    int wid  = tid >> 6;
    int lane = tid & 63;

    __shared__ float sa[4 * KC];   // attn tile [4][KC]

    // Per-lane vp fragments: 4 rows x 16 floats (float4 at lane + 64q).
    const float4* vp4 = (const float4*)vp;
    float4 a0q0 = vp4[(size_t)(n0+0)*256 + lane      ];
    float4 a0q1 = vp4[(size_t)(n0+0)*256 + lane +  64];
    float4 a0q2 = vp4[(size_t)(n0+0)*256 + lane + 128];
    float4 a0q3 = vp4[(size_t)(n0+0)*256 + lane + 192];
    float4 a1q0 = vp4[(size_t)(n0+1)*256 + lane      ];
    float4 a1q1 = vp4[(size_t)(n0+1)*256 + lane +  64];
    float4 a1q2 = vp4[(size_t)(n0+1)*256 + lane + 128];
    float4 a1q3 = vp4[(size_t)(n0+1)*256 + lane + 192];
    float4 a2q0 = vp4[(size_t)(n0+2)*256 + lane      ];
    float4 a2q1 = vp4[(size_t)(n0+2)*256 + lane +  64];
    float4 a2q2 = vp4[(size_t)(n0+2)*256 + lane + 128];
    float4 a2q3 = vp4[(size_t)(n0+2)*256 + lane + 192];
    float4 a3q0 = vp4[(size_t)(n0+3)*256 + lane      ];
    float4 a3q1 = vp4[(size_t)(n0+3)*256 + lane +  64];
    float4 a3q2 = vp4[(size_t)(n0+3)*256 + lane + 128];
    float4 a3q3 = vp4[(size_t)(n0+3)*256 + lane + 192];

    constexpr int EPW = KC / 4;    // e's per wave (8 for KC=32)
#pragma unroll
    for (int ei = 0; ei < EPW; ++ei) {
        int kk = wid * EPW + ei;
        int e  = k0 + kk;
        const float4* Br = (const float4*)(Wo + (size_t)e * EDIM);
        float4 b0 = Br[lane], b1 = Br[lane + 64], b2 = Br[lane + 128], b3 = Br[lane + 192];

        float s0 = a0q0.x*b0.x + a0q0.y*b0.y + a0q0.z*b0.z + a0q0.w*b0.w
                 + a0q1.x*b1.x + a0q1.y*b1.y + a0q1.z*b1.z + a0q1.w*b1.w
                 + a0q2.x*b2.x + a0q2.y*b2.y + a0q2.z*b2.z + a0q2.w*b2.w
                 + a0q3.x*b3.x + a0q3.y*b3.y + a0q3.z*b3.z + a0q3.w*b3.w;
        float s1 = a1q0.x*b0.x + a1q0.y*b0.y + a1q0.z*b0.z + a1q0.w*b0.w
                 + a1q1.x*b1.x + a1q1.y*b1.y + a1q1.z*b1.z + a1q1.w*b1.w
                 + a1q2.x*b2.x + a1q2.y*b2.y + a1q2.z*b2.z + a1q2.w*b2.w
                 + a1q3.x*b3.x + a1q3.y*b3.y + a1q3.z*b3.z + a1q3.w*b3.w;
        float s2 = a2q0.x*b0.x + a2q0.y*b0.y + a2q0.z*b0.z + a2q0.w*b0.w
                 + a2q1.x*b1.x + a2q1.y*b1.y + a2q1.z*b1.z + a2q1.w*b1.w
                 + a2q2.x*b2.x + a2q2.y*b2.y + a2q2.z*b2.z + a2q2.w*b2.w
                 + a2q3.x*b3.x + a2q3.y*b3.y + a2q3.z*b3.z + a2q3.w*b3.w;
        float s3 = a3q0.x*b0.x + a3q0.y*b0.y + a3q0.z*b0.z + a3q0.w*b0.w
                 + a3q1.x*b1.x + a3q1.y*b1.y + a3q1.z*b1.z + a3q1.w*b1.w
                 + a3q2.x*b2.x + a3q2.y*b2.y + a3q2.z*b2.z + a3q2.w*b2.w
                 + a3q3.x*b3.x + a3q3.y*b3.y + a3q3.z*b3.z + a3q3.w*b3.w;

#pragma unroll
        for (int off = 32; off > 0; off >>= 1) {
            s0 += __shfl_down(s0, off);
            s1 += __shfl_down(s1, off);
            s2 += __shfl_down(s2, off);
            s3 += __shfl_down(s3, off);
        }
        if (lane == 0) {
            float be = bo[e];
            sa[0 * KC + kk] = s0 + be;
            sa[1 * KC + kk] = s1 + be;
            sa[2 * KC + kk] = s2 + be;
            sa[3 * KC + kk] = s3 + be;
        }
    }
    __syncthreads();

    // ---- audio partial: out[n0+.][4t..4t+3] += sum_k sa[.][k] * conn[k0+k][4t..] ----
    const float4* c4 = (const float4*)conn;   // 1024 float4 per row (4096 cols)
    float4 acc0 = {0,0,0,0}, acc1 = {0,0,0,0}, acc2 = {0,0,0,0}, acc3 = {0,0,0,0};
#pragma unroll 4
    for (int k = 0; k < KC; ++k) {
        float4 c = c4[(size_t)(k0 + k) * 1024 + tid];
        float v0 = sa[k], v1 = sa[KC + k], v2 = sa[2 * KC + k], v3 = sa[3 * KC + k];
        acc0.x += v0*c.x; acc0.y += v0*c.y; acc0.z += v0*c.z; acc0.w += v0*c.w;
        acc1.x += v1*c.x; acc1.y += v1*c.y; acc1.z += v1*c.z; acc1.w += v1*c.w;
        acc2.x += v2*c.x; acc2.y += v2*c.y; acc2.z += v2*c.z; acc2.w += v2*c.w;
        acc3.x += v3*c.x; acc3.y += v3*c.y; acc3.z += v3*c.z; acc3.w += v3*c.w;
    }

    float* o0 = out + (size_t)(n0 + 0) * 1024 + 4 * tid;
    float* o1 = out + (size_t)(n0 + 1) * 1024 + 4 * tid;
    float* o2 = out + (size_t)(n0 + 2) * 1024 + 4 * tid;
    float* o3 = out + (size_t)(n0 + 3) * 1024 + 4 * tid;
    atomicAdd(o0 + 0, acc0.x); atomicAdd(o0 + 1, acc0.y); atomicAdd(o0 + 2, acc0.z); atomicAdd(o0 + 3, acc0.w);
    atomicAdd(o1 + 0, acc1.x); atomicAdd(o1 + 1, acc1.y); atomicAdd(o1 + 2, acc1.z); atomicAdd(o1 + 3, acc1.w);
    atomicAdd(o2 + 0, acc2.x); atomicAdd(o2 + 1, acc2.y); atomicAdd(o2 + 2, acc2.z); atomicAdd(o2 + 3, acc2.w);
    atomicAdd(o3 + 0, acc3.x); atomicAdd(o3 + 1, acc3.y); atomicAdd(o3 + 2, acc3.z); atomicAdd(o3 + 3, acc3.w);
}

extern "C" void kernel_launch(void* const* d_in, const int* in_sizes, int n_in,
                              void* d_out, int out_size, void* d_ws, size_t ws_size,
                              hipStream_t stream) {
    // setup_inputs order:
    // 0 av_value, 1 av_key, 2 av_query, 3 in_proj_w, 4 in_proj_b,
    // 5 out_proj_w, 6 out_proj_b, 7 connections
    const float* av_value   = (const float*)d_in[0];
    const float* in_proj_w  = (const float*)d_in[3];
    const float* in_proj_b  = (const float*)d_in[4];
    const float* out_proj_w = (const float*)d_in[5];
    const float* out_proj_b = (const float*)d_in[6];
    const float* conn       = (const float*)d_in[7];
    float* out = (float*)d_out;

    float* vp = (float*)d_ws;              // 32x1024 scratch

    // Dispatch A: vp = av_value @ Wv^T + bv, plus full output copy/zero.
    gemm1_copy_kernel<<<A_BLOCKS, 256, 0, stream>>>(
        av_value, in_proj_w + 2 * EDIM * EDIM, in_proj_b + 2 * EDIM, vp,
        (const float4*)conn, (const float4*)in_proj_w,
        (const float4*)out_proj_w, (float4*)out);

    // Dispatch B: fused gemm2 + audio (attn never materialized).
    tail_kernel<<<NB_TAIL, 256, 0, stream>>>(
        vp, out_proj_w, out_proj_b, conn, out);
}